// Round 1
// baseline (143.113 us; speedup 1.0000x reference)
//
#include <hip/hip_runtime.h>

#define BB 4
#define CC 16
#define HH 256
#define WW 256
#define OO 32
#define LL (HH * WW)

__global__ __launch_bounds__(256) void dynaconv_kernel(
    const float* __restrict__ x,    // [B, C, H, W]
    const float* __restrict__ W1,   // [O, 144]
    const float* __restrict__ b1,   // [O]
    const float* __restrict__ W2,   // [288, O]
    const float* __restrict__ b2,   // [288]
    const float* __restrict__ bias, // [O]
    float* __restrict__ out)        // [B, O, H, W]
{
    const int p = blockIdx.x * 256 + threadIdx.x;   // pixel over B*L
    const int b = p >> 16;                          // / 65536
    const int l = p & 65535;
    const int h = l >> 8;
    const int w = l & 255;

    const float* xb = x + b * (CC * LL);

    float hid[OO];
#pragma unroll
    for (int o = 0; o < OO; ++o) hid[o] = b1[o];

    float pc[9];
#pragma unroll
    for (int k = 0; k < 9; ++k) pc[k] = 0.f;

    // ---- Phase 1: feat = im2col patch; hid = feat @ W1^T + b1; pc[k] = sum_c feat ----
#pragma unroll 1
    for (int c = 0; c < CC; ++c) {
        const float* xc = xb + c * LL;
        float f[9];
#pragma unroll
        for (int i = 0; i < 3; ++i) {
            const int hh = h + i - 1;
            const bool rok = (unsigned)hh < (unsigned)HH;
#pragma unroll
            for (int j = 0; j < 3; ++j) {
                const int ww = w + j - 1;
                const bool ok = rok && ((unsigned)ww < (unsigned)WW);
                f[i * 3 + j] = ok ? xc[hh * WW + ww] : 0.f;
            }
        }
#pragma unroll
        for (int k = 0; k < 9; ++k) pc[k] += f[k];
#pragma unroll
        for (int o = 0; o < OO; ++o) {
            const float* w1r = W1 + o * 144 + c * 9;
#pragma unroll
            for (int k = 0; k < 9; ++k) hid[o] = fmaf(f[k], w1r[k], hid[o]);
        }
    }

    // ---- tanh (fast: tanh(x) = 1 - 2/(e^{2x}+1)) ----
#pragma unroll
    for (int o = 0; o < OO; ++o) {
        const float e = __expf(2.f * hid[o]);
        hid[o] = 1.f - 2.f / (e + 1.f);
    }

    // ---- Phase 2: kern[g] = hid @ W2[g,:] + b2[g]; out[o] = sum_k kern[o*9+k]*pc[k] ----
    float* ob = out + b * (OO * LL) + l;
#pragma unroll 1
    for (int o = 0; o < OO; ++o) {
        float acc = 0.f;
#pragma unroll
        for (int k = 0; k < 9; ++k) {
            const int g = o * 9 + k;
            const float* w2r = W2 + g * OO;
            float kv = b2[g];
#pragma unroll
            for (int h2 = 0; h2 < OO; ++h2) kv = fmaf(hid[h2], w2r[h2], kv);
            acc = fmaf(kv, pc[k], acc);
        }
        ob[o * LL] = acc + bias[o];
    }
}

extern "C" void kernel_launch(void* const* d_in, const int* in_sizes, int n_in,
                              void* d_out, int out_size, void* d_ws, size_t ws_size,
                              hipStream_t stream) {
    const float* x    = (const float*)d_in[0];
    const float* W1   = (const float*)d_in[1];
    const float* b1   = (const float*)d_in[2];
    const float* W2   = (const float*)d_in[3];
    const float* b2   = (const float*)d_in[4];
    const float* bias = (const float*)d_in[5];
    float* out = (float*)d_out;

    const int total = BB * LL;                 // 262144 pixels
    dynaconv_kernel<<<total / 256, 256, 0, stream>>>(x, W1, b1, W2, b2, bias, out);
}

// Round 2
// 68.124 us; speedup vs baseline: 2.1008x; 2.1008x over previous
//
#include <hip/hip_runtime.h>
#include <hip/hip_bf16.h>

#define BB 4
#define CC 16
#define OO 32
#define LL 65536   // 256*256

typedef __attribute__((ext_vector_type(8))) short bf16x8;
typedef __attribute__((ext_vector_type(4))) float f32x4;

static __device__ __forceinline__ ushort f2b(float f) {
    union { float f; unsigned u; } v; v.f = f;
    return (ushort)((v.u + 0x7fff + ((v.u >> 16) & 1)) >> 16);
}
static __device__ __forceinline__ float b2f(ushort b) {
    union { unsigned u; float f; } v; v.u = ((unsigned)b) << 16;
    return v.f;
}

// ---- pre-pass: pack W1 (r-major permuted, +b1 col, K=160) and W2 (+b2/bias cols, K=320) to bf16 ----
// W1e[o][kk=r*16+c] = W1[o][c*9+r] (r<9); [144]=b1[o]; else 0.          (32x160)
// W2p[o][kk=k*32+h] = W2[(o*9+k)][h] = W2flat[o*288+kk] (kk<288);
//        [288+k]=b2[o*9+k] (k<9); [297]=bias[o]; else 0.                (32x320)
__global__ void prepass(const float* __restrict__ W1, const float* __restrict__ b1,
                        const float* __restrict__ W2, const float* __restrict__ b2,
                        const float* __restrict__ bias,
                        ushort* __restrict__ w1e, ushort* __restrict__ w2p) {
    int idx = blockIdx.x * 256 + threadIdx.x;
    if (idx < 32 * 160) {
        int o = idx / 160, kk = idx % 160;
        float v;
        if (kk < 144)       v = W1[o * 144 + (kk & 15) * 9 + (kk >> 4)];
        else if (kk == 144) v = b1[o];
        else                v = 0.f;
        w1e[idx] = f2b(v);
    } else if (idx < 32 * 160 + 32 * 320) {
        int j = idx - 32 * 160;
        int o = j / 320, kk = j % 320;
        float v;
        if (kk < 288)       v = W2[o * 288 + kk];
        else if (kk < 297)  v = b2[o * 9 + (kk - 288)];
        else if (kk == 297) v = bias[o];
        else                v = 0.f;
        w2p[j] = f2b(v);
    }
}

// ---- main: 1 block = 4 waves, each wave = 16 consecutive pixels in one image row ----
__global__ __launch_bounds__(256, 4) void dynaconv_mfma(
    const float* __restrict__ x, const ushort* __restrict__ w1e,
    const ushort* __restrict__ w2p, float* __restrict__ out)
{
    __shared__ ushort hidL[4][16][40];   // per-wave hid bf16, padded stride
    __shared__ float  outL[4][16][36];   // per-wave out transpose buffer

    const int tid  = threadIdx.x;
    const int wv   = tid >> 6;
    const int lane = tid & 63;
    const int g    = lane >> 4;    // lane group 0..3 (K-block)
    const int lm   = lane & 15;    // A-row (pixel) / B-row (output col)

    const int p0 = blockIdx.x * 64;
    const int b  = p0 >> 16;
    const int h  = (p0 >> 8) & 255;
    const int w0 = (p0 & 255) + wv * 16;
    const int w  = w0 + lm;

    const float* xb = x + b * (CC * LL);
    const int c0 = (g & 1) * 8;    // channel slice for this lane

    // ---------------- Phase 1: hid = feat @ W1e^T  (K=160, r-major) ----------------
    f32x4 acc1[2] = {{0.f,0.f,0.f,0.f},{0.f,0.f,0.f,0.f}};
    float s[5];

#pragma unroll
    for (int ks = 0; ks < 5; ++ks) {
        bf16x8 af;
        float ps = 0.f;
        const int r = 2 * ks + (g >> 1);     // neighbor index for this lane
        if (r <= 8) {
            const int di = r / 3 - 1, dj = r % 3 - 1;
            const int hh = h + di, ww = w + dj;
            const bool ok = ((unsigned)hh < 256u) && ((unsigned)ww < 256u);
            const int idx0 = ok ? (c0 * LL + hh * 256 + ww) : 0;
            const float* pl = xb + idx0;
#pragma unroll
            for (int j = 0; j < 8; ++j) {
                float v = pl[j * LL];
                v = ok ? v : 0.f;
                ps += v;
                af[j] = (short)f2b(v);
            }
        } else {                              // ks==4, groups 2/3: bias column block
#pragma unroll
            for (int j = 0; j < 8; ++j) af[j] = 0;
            if (g == 2) af[0] = (short)0x3F80;   // feat[.][144] = 1.0
        }
        s[ks] = ps;
#pragma unroll
        for (int nt = 0; nt < 2; ++nt) {
            bf16x8 bfm = *(const bf16x8*)(w1e + (lm + nt * 16) * 160 + ks * 32 + g * 8);
            acc1[nt] = __builtin_amdgcn_mfma_f32_16x16x32_bf16(af, bfm, acc1[nt], 0, 0, 0);
        }
    }

    // ---------------- pc[r]: channel sums, gathered per lane's pixel lm ----------------
    float tarr[5];
#pragma unroll
    for (int ks = 0; ks < 5; ++ks)
        tarr[ks] = s[ks] + __shfl_xor(s[ks], 16);
    // lanes<32 hold pc[2ks] for pixel lm; lanes>=32 hold pc[2ks+1]
    float pcv[9];
#pragma unroll
    for (int r = 0; r < 9; ++r)
        pcv[r] = __shfl(tarr[r >> 1], lm + ((r & 1) << 5));

    // ---------------- tanh -> hid bf16 -> LDS transpose ----------------
#pragma unroll
    for (int nt = 0; nt < 2; ++nt)
#pragma unroll
        for (int q = 0; q < 4; ++q) {
            float e  = __expf(2.f * acc1[nt][q]);
            float th = 1.f - 2.f / (e + 1.f);
            hidL[wv][g * 4 + q][lm + nt * 16] = f2b(th);
        }
    __syncthreads();
    bf16x8 hv = *(const bf16x8*)&hidL[wv][lm][g * 8];
    float hf[8];
#pragma unroll
    for (int j = 0; j < 8; ++j) hf[j] = b2f((ushort)hv[j]);

    // ---------------- Phase 2: out = (pc ⊗ hid) @ W2p^T  (K=320, k-major) ----------------
    f32x4 acc2[2] = {{0.f,0.f,0.f,0.f},{0.f,0.f,0.f,0.f}};
#pragma unroll
    for (int ks = 0; ks < 10; ++ks) {
        bf16x8 af;
        if (ks < 9) {
#pragma unroll
            for (int j = 0; j < 8; ++j) af[j] = (short)f2b(hf[j] * pcv[ks]);
        } else {                              // extension block: pc terms, bias
#pragma unroll
            for (int j = 0; j < 8; ++j) {
                float v;
                if      (g == 0) v = pcv[j];
                else if (g == 1) v = (j == 0) ? pcv[8] : ((j == 1) ? 1.f : 0.f);
                else             v = 0.f;
                af[j] = (short)f2b(v);
            }
        }
#pragma unroll
        for (int nt = 0; nt < 2; ++nt) {
            bf16x8 bfm = *(const bf16x8*)(w2p + (lm + nt * 16) * 320 + ks * 32 + g * 8);
            acc2[nt] = __builtin_amdgcn_mfma_f32_16x16x32_bf16(af, bfm, acc2[nt], 0, 0, 0);
        }
    }

    // ---------------- epilogue: LDS transpose -> coalesced stores ----------------
#pragma unroll
    for (int nt = 0; nt < 2; ++nt)
#pragma unroll
        for (int q = 0; q < 4; ++q)
            outL[wv][g * 4 + q][lm + nt * 16] = acc2[nt][q];
    __syncthreads();
    float* ob = out + b * (OO * LL) + h * 256 + w0;
#pragma unroll
    for (int i = 0; i < 8; ++i) {
        const int o = i * 4 + g;
        ob[o * LL + lm] = outL[wv][lm][o];
    }
}

extern "C" void kernel_launch(void* const* d_in, const int* in_sizes, int n_in,
                              void* d_out, int out_size, void* d_ws, size_t ws_size,
                              hipStream_t stream) {
    const float* x    = (const float*)d_in[0];
    const float* W1   = (const float*)d_in[1];
    const float* b1   = (const float*)d_in[2];
    const float* W2   = (const float*)d_in[3];
    const float* b2   = (const float*)d_in[4];
    const float* bias = (const float*)d_in[5];
    float* out = (float*)d_out;

    ushort* w1e = (ushort*)d_ws;            // 32*160 bf16
    ushort* w2p = w1e + 32 * 160;           // 32*320 bf16

    prepass<<<60, 256, 0, stream>>>(W1, b1, W2, b2, bias, w1e, w2p);
    dynaconv_mfma<<<4096, 256, 0, stream>>>(x, w1e, w2p, out);
}

// Round 3
// 32.453 us; speedup vs baseline: 4.4098x; 2.0991x over previous
//
#include <hip/hip_runtime.h>

#define CC 16
#define OO 32
#define LL 65536   // 256*256

typedef __attribute__((ext_vector_type(8))) short bf16x8;
typedef __attribute__((ext_vector_type(4))) float f32x4;
typedef __attribute__((ext_vector_type(4))) int   i32x4;

static __device__ __forceinline__ ushort f2b(float f) {   // exact RNE (prepass)
    union { float f; unsigned u; } v; v.f = f;
    return (ushort)((v.u + 0x7fff + ((v.u >> 16) & 1)) >> 16);
}
// pack two floats -> (bf16(fh)<<16)|bf16(fl), round-half-up: 3 ops
static __device__ __forceinline__ unsigned pk2(float fl, float fh) {
    unsigned ul = __float_as_uint(fl) + 0x8000u;
    unsigned uh = __float_as_uint(fh) + 0x8000u;
    return __builtin_amdgcn_perm(uh, ul, 0x07060302);
}

// ---- prepass: weights -> bf16, laid out in exact MFMA A-fragment order ----
// w1f: frag f=ks*2+ot (ks<5), elem ((f*64+lane)*8+j) = W1e[ot*16+(lane&15)][ks*32+(lane>>4)*8+j]
//   W1e[o][kk] (kk=r*16+c): kk<144 -> W1[o*144+c*9+r]; kk==144 -> b1[o]; else 0
// w2f: frag f=ks*2+ot (ks<10): W2p[o][kk]: kk<288 -> W2flat[o*288+kk];
//   kk<297 -> b2[o*9+kk-288]; kk==297 -> bias[o]; else 0
__global__ void prepass(const float* __restrict__ W1, const float* __restrict__ b1,
                        const float* __restrict__ W2, const float* __restrict__ b2,
                        const float* __restrict__ bias,
                        ushort* __restrict__ w1f, ushort* __restrict__ w2f) {
    int idx = blockIdx.x * 256 + threadIdx.x;
    if (idx < 5120) {
        int f = idx >> 9, lane = (idx >> 3) & 63, j = idx & 7;
        int ks = f >> 1, ot = f & 1, lm = lane & 15, g = lane >> 4;
        int o = ot * 16 + lm, kk = ks * 32 + g * 8 + j;
        int r = kk >> 4, c = kk & 15;
        float v = (kk < 144) ? W1[o * 144 + c * 9 + r] : (kk == 144 ? b1[o] : 0.f);
        w1f[idx] = f2b(v);
    } else if (idx < 15360) {
        int i2 = idx - 5120;
        int f = i2 >> 9, lane = (i2 >> 3) & 63, j = i2 & 7;
        int ks = f >> 1, ot = f & 1, lm = lane & 15, g = lane >> 4;
        int o = ot * 16 + lm, kk = ks * 32 + g * 8 + j;
        float v;
        if      (kk < 288) v = W2[o * 288 + kk];
        else if (kk < 297) v = b2[o * 9 + (kk - 288)];
        else if (kk == 297) v = bias[o];
        else               v = 0.f;
        w2f[i2] = f2b(v);
    }
}

// ---- main: 1 block = 1 image row (b,h); 4 waves x 4 tiles of 16 pixels ----
__global__ __launch_bounds__(256, 2) void dynaconv_mfma(
    const float* __restrict__ x, const ushort* __restrict__ w1f,
    const ushort* __restrict__ w2f, float* __restrict__ out)
{
    __shared__ __align__(16) ushort xs[3][260][24];  // bf16 x, [row-1..+1][w+1][c], halo cols 0/257 = 0
    __shared__ __align__(16) float  S[3][260];       // fp32 channel sums (pc lookup)
    __shared__ __align__(16) float  hidT[4][16][36]; // per-wave hid transpose (no barrier needed)

    const int tid  = threadIdx.x;
    const int wv   = tid >> 6;
    const int lane = tid & 63;
    const int g    = lane >> 4;
    const int lm   = lane & 15;
    const int b    = blockIdx.x >> 8;
    const int h    = blockIdx.x & 255;

    // ---- weight fragments -> VGPRs (once per block, coalesced 16B/lane) ----
    bf16x8 W1R[10], W2R[20];
#pragma unroll
    for (int f = 0; f < 10; ++f) W1R[f] = *(const bf16x8*)(w1f + (f * 64 + lane) * 8);
#pragma unroll
    for (int f = 0; f < 20; ++f) W2R[f] = *(const bf16x8*)(w2f + (f * 64 + lane) * 8);

    // ---- stage x row-band (3 rows x 256 cols x 16 ch) -> bf16 LDS + fp32 channel sums ----
    const float* xb = x + b * (CC * LL);
    {
        float s0 = 0.f, s1 = 0.f, s2 = 0.f;
#pragma unroll
        for (int cp = 0; cp < 8; ++cp) {
            const float* p0 = xb + (2 * cp) * LL;
            const float* p1 = p0 + LL;
#pragma unroll
            for (int r = 0; r < 3; ++r) {
                const int hh = h - 1 + r;
                const bool ok = (unsigned)hh < 256u;
                const int off = (ok ? hh : 0) * 256 + tid;
                float va = p0[off], vb = p1[off];
                va = ok ? va : 0.f; vb = ok ? vb : 0.f;
                if (r == 0) s0 += va + vb; else if (r == 1) s1 += va + vb; else s2 += va + vb;
                *(unsigned*)&xs[r][tid + 1][2 * cp] = pk2(va, vb);
            }
        }
        S[0][tid + 1] = s0; S[1][tid + 1] = s1; S[2][tid + 1] = s2;
        if (tid < 96) {  // zero halo cols of xs
            int r = tid >> 5, side = (tid >> 4) & 1, c = tid & 15;
            xs[r][side * 257][c] = 0;
        }
        if (tid < 6) S[tid >> 1][(tid & 1) * 257] = 0.f;
    }
    __syncthreads();   // the only barrier

    // ---- per-ks feat LDS offsets (ushort units), loop-invariant ----
    int soff[5];
#pragma unroll
    for (int ks = 0; ks < 5; ++ks) {
        int r = 2 * ks + (g >> 1); if (r > 8) r = 8;
        int r3 = (r * 11) >> 5, rm = r - 3 * r3;
        soff[ks] = (r3 * 260 + rm + lm) * 24 + (g & 1) * 8;
    }
    const ushort* xsf = &xs[0][0][0];

#pragma unroll
    for (int t = 0; t < 4; ++t) {
        const int w0t = wv * 64 + t * 16;
        const int tb = w0t * 24;

        // ---- phase 1: hid[o, pixel] = W1e @ feat ----
        f32x4 a1[2] = {{0.f,0.f,0.f,0.f},{0.f,0.f,0.f,0.f}};
#pragma unroll
        for (int ks = 0; ks < 5; ++ks) {
            bf16x8 ff = *(const bf16x8*)(xsf + soff[ks] + tb);
            if (ks == 4) {               // g>=2: bias-extension K block
                i32x4 wd = *(i32x4*)&ff;
                wd[0] = (g < 2) ? wd[0] : (g == 2 ? 0x3F80 : 0);
                wd[1] = (g < 2) ? wd[1] : 0;
                wd[2] = (g < 2) ? wd[2] : 0;
                wd[3] = (g < 2) ? wd[3] : 0;
                ff = *(bf16x8*)&wd;
            }
            a1[0] = __builtin_amdgcn_mfma_f32_16x16x32_bf16(W1R[2 * ks],     ff, a1[0], 0, 0, 0);
            a1[1] = __builtin_amdgcn_mfma_f32_16x16x32_bf16(W1R[2 * ks + 1], ff, a1[1], 0, 0, 0);
        }

        // ---- tanh -> hidT (wave-private, no barrier) ----
#pragma unroll
        for (int ot = 0; ot < 2; ++ot)
#pragma unroll
            for (int q = 0; q < 4; ++q) {
                float e = __expf(2.f * a1[ot][q]);
                hidT[wv][lm][ot * 16 + g * 4 + q] = 1.f - 2.f / (e + 1.f);
            }
        f32x4 h0 = *(const f32x4*)&hidT[wv][lm][g * 8];
        f32x4 h1 = *(const f32x4*)&hidT[wv][lm][g * 8 + 4];

        float pcv[9];
#pragma unroll
        for (int r = 0; r < 9; ++r) pcv[r] = S[r / 3][w0t + lm + (r % 3)];

        // ---- phase 2: out[o,pixel] = W2p @ (pc ⊗ hid) ----
        f32x4 a2[2] = {{0.f,0.f,0.f,0.f},{0.f,0.f,0.f,0.f}};
#pragma unroll
        for (int ks = 0; ks < 9; ++ks) {
            const float p = pcv[ks];
            i32x4 wd;
            wd[0] = (int)pk2(h0[0] * p, h0[1] * p);
            wd[1] = (int)pk2(h0[2] * p, h0[3] * p);
            wd[2] = (int)pk2(h1[0] * p, h1[1] * p);
            wd[3] = (int)pk2(h1[2] * p, h1[3] * p);
            bf16x8 ff2 = *(bf16x8*)&wd;
            a2[0] = __builtin_amdgcn_mfma_f32_16x16x32_bf16(W2R[2 * ks],     ff2, a2[0], 0, 0, 0);
            a2[1] = __builtin_amdgcn_mfma_f32_16x16x32_bf16(W2R[2 * ks + 1], ff2, a2[1], 0, 0, 0);
        }
        {   // ks==9: K-extension block (b2·pc + bias)
            i32x4 wd;
            wd[0] = (g == 0) ? (int)pk2(pcv[0], pcv[1]) : ((g == 1) ? (int)pk2(pcv[8], 1.f) : 0);
            wd[1] = (g == 0) ? (int)pk2(pcv[2], pcv[3]) : 0;
            wd[2] = (g == 0) ? (int)pk2(pcv[4], pcv[5]) : 0;
            wd[3] = (g == 0) ? (int)pk2(pcv[6], pcv[7]) : 0;
            bf16x8 ff2 = *(bf16x8*)&wd;
            a2[0] = __builtin_amdgcn_mfma_f32_16x16x32_bf16(W2R[18], ff2, a2[0], 0, 0, 0);
            a2[1] = __builtin_amdgcn_mfma_f32_16x16x32_bf16(W2R[19], ff2, a2[1], 0, 0, 0);
        }

        // ---- stores straight from accumulator: D[o = ot*16+g*4+q][pixel lm] ----
        float* ob = out + b * (OO * LL) + h * 256 + w0t + lm;
#pragma unroll
        for (int ot = 0; ot < 2; ++ot)
#pragma unroll
            for (int q = 0; q < 4; ++q)
                ob[(ot * 16 + g * 4 + q) * LL] = a2[ot][q];
    }
}

extern "C" void kernel_launch(void* const* d_in, const int* in_sizes, int n_in,
                              void* d_out, int out_size, void* d_ws, size_t ws_size,
                              hipStream_t stream) {
    const float* x    = (const float*)d_in[0];
    const float* W1   = (const float*)d_in[1];
    const float* b1   = (const float*)d_in[2];
    const float* W2   = (const float*)d_in[3];
    const float* b2   = (const float*)d_in[4];
    const float* bias = (const float*)d_in[5];
    float* out = (float*)d_out;

    ushort* w1f = (ushort*)d_ws;        // 5120 bf16
    ushort* w2f = w1f + 5120;           // 10240 bf16

    prepass<<<60, 256, 0, stream>>>(W1, b1, W2, b2, bias, w1f, w2f);
    dynaconv_mfma<<<1024, 256, 0, stream>>>(x, w1f, w2f, out);
}

// Round 4
// 26.829 us; speedup vs baseline: 5.3344x; 1.2097x over previous
//
#include <hip/hip_runtime.h>

#define CC 16
#define OO 32
#define LL 65536   // 256*256

typedef __attribute__((ext_vector_type(8))) short bf16x8;
typedef __attribute__((ext_vector_type(4))) float f32x4;
typedef __attribute__((ext_vector_type(4))) int   i32x4;

static __device__ __forceinline__ ushort f2b(float f) {   // exact RNE (prepass)
    union { float f; unsigned u; } v; v.f = f;
    return (ushort)((v.u + 0x7fff + ((v.u >> 16) & 1)) >> 16);
}
// pack two floats -> (bf16(fh)<<16)|bf16(fl), round-half-up
static __device__ __forceinline__ unsigned pk2(float fl, float fh) {
    unsigned ul = __float_as_uint(fl) + 0x8000u;
    unsigned uh = __float_as_uint(fh) + 0x8000u;
    return __builtin_amdgcn_perm(uh, ul, 0x07060302);
}

// ---- prepass: weights -> bf16 in exact MFMA A-fragment order (unchanged from R3) ----
__global__ void prepass(const float* __restrict__ W1, const float* __restrict__ b1,
                        const float* __restrict__ W2, const float* __restrict__ b2,
                        const float* __restrict__ bias,
                        ushort* __restrict__ w1f, ushort* __restrict__ w2f) {
    int idx = blockIdx.x * 256 + threadIdx.x;
    if (idx < 5120) {
        int f = idx >> 9, lane = (idx >> 3) & 63, j = idx & 7;
        int ks = f >> 1, ot = f & 1, lm = lane & 15, g = lane >> 4;
        int o = ot * 16 + lm, kk = ks * 32 + g * 8 + j;
        int r = kk >> 4, c = kk & 15;
        float v = (kk < 144) ? W1[o * 144 + c * 9 + r] : (kk == 144 ? b1[o] : 0.f);
        w1f[idx] = f2b(v);
    } else if (idx < 15360) {
        int i2 = idx - 5120;
        int f = i2 >> 9, lane = (i2 >> 3) & 63, j = i2 & 7;
        int ks = f >> 1, ot = f & 1, lm = lane & 15, g = lane >> 4;
        int o = ot * 16 + lm, kk = ks * 32 + g * 8 + j;
        float v;
        if      (kk < 288) v = W2[o * 288 + kk];
        else if (kk < 297) v = b2[o * 9 + (kk - 288)];
        else if (kk == 297) v = bias[o];
        else               v = 0.f;
        w2f[i2] = f2b(v);
    }
}

// ---- main: 1 block = 2 image rows; 512 blocks = 2 resident/CU; XCD-chunked swizzle ----
__global__ __launch_bounds__(256, 2) void dynaconv_mfma(
    const float* __restrict__ x, const ushort* __restrict__ w1f,
    const ushort* __restrict__ w2f, float* __restrict__ out)
{
    __shared__ __align__(16) ushort xs[4][260][24];  // bf16 x, rows h0-1..h0+2, halo cols 0/257=0
    __shared__ __align__(16) float  S[4][260];       // fp32 channel sums
    __shared__ __align__(16) float  hidT[4][16][36]; // per-wave hid transpose (wave-private)

    const int tid  = threadIdx.x;
    const int wv   = tid >> 6;
    const int lane = tid & 63;
    const int g    = lane >> 4;
    const int lm   = lane & 15;

    // XCD-chunked swizzle: blocks on one XCD process consecutive row-pairs (L2 reuse)
    const int vbid = (blockIdx.x & 7) * 64 + (blockIdx.x >> 3);   // 512 = 8*64, bijective
    const int b    = vbid >> 7;
    const int h0   = (vbid & 127) * 2;

    // ---- weight fragments -> regs (once per block) ----
    bf16x8 W1R[10], W2R[20];
#pragma unroll
    for (int f = 0; f < 10; ++f) W1R[f] = *(const bf16x8*)(w1f + (f * 64 + lane) * 8);
#pragma unroll
    for (int f = 0; f < 20; ++f) W2R[f] = *(const bf16x8*)(w2f + (f * 64 + lane) * 8);

    // ---- stage 4 rows x 256 cols x 16 ch -> bf16 LDS + fp32 channel sums ----
    const float* xb = x + b * (CC * LL);
    {
        int offr[4]; bool okr[4];
#pragma unroll
        for (int r = 0; r < 4; ++r) {
            const int hh = h0 - 1 + r;
            okr[r] = (unsigned)hh < 256u;
            offr[r] = (okr[r] ? hh : 0) * 256 + tid;
        }
        float sr[4] = {0.f, 0.f, 0.f, 0.f};
#pragma unroll
        for (int cp = 0; cp < 8; ++cp) {
            const float* p0 = xb + (2 * cp) * LL;
            const float* p1 = p0 + LL;
#pragma unroll
            for (int r = 0; r < 4; ++r) {
                float va = p0[offr[r]], vb = p1[offr[r]];
                va = okr[r] ? va : 0.f; vb = okr[r] ? vb : 0.f;
                sr[r] += va + vb;
                *(unsigned*)&xs[r][tid + 1][2 * cp] = pk2(va, vb);
            }
        }
#pragma unroll
        for (int r = 0; r < 4; ++r) S[r][tid + 1] = sr[r];
        if (tid < 128) { int r = tid >> 5, side = (tid >> 4) & 1, c = tid & 15; xs[r][side * 257][c] = 0; }
        if (tid < 8)   S[tid >> 1][(tid & 1) * 257] = 0.f;
    }
    __syncthreads();   // the only barrier

    // per-ks feat LDS offsets (ushort units), loop-invariant
    int soff[5];
#pragma unroll
    for (int ks = 0; ks < 5; ++ks) {
        int r = 2 * ks + (g >> 1); if (r > 8) r = 8;
        int r3 = (r * 11) >> 5, rm = r - 3 * r3;
        soff[ks] = (r3 * 260 + rm + lm) * 24 + (g & 1) * 8;
    }
    const ushort* xsf = &xs[0][0][0];

    for (int hr = 0; hr < 2; ++hr) {
        const int hb = hr * (260 * 24);
#pragma unroll
        for (int t = 0; t < 4; ++t) {
            const int w0t = wv * 64 + t * 16;
            const int tb = w0t * 24 + hb;

            // ---- phase 1: hid[o,pixel] = W1e @ feat ----
            f32x4 a1[2] = {{0.f,0.f,0.f,0.f},{0.f,0.f,0.f,0.f}};
#pragma unroll
            for (int ks = 0; ks < 5; ++ks) {
                bf16x8 ff = *(const bf16x8*)(xsf + soff[ks] + tb);
                if (ks == 4) {               // g>=2: bias-extension K block
                    i32x4 wd = *(i32x4*)&ff;
                    wd[0] = (g < 2) ? wd[0] : (g == 2 ? 0x3F80 : 0);
                    wd[1] = (g < 2) ? wd[1] : 0;
                    wd[2] = (g < 2) ? wd[2] : 0;
                    wd[3] = (g < 2) ? wd[3] : 0;
                    ff = *(bf16x8*)&wd;
                }
                a1[0] = __builtin_amdgcn_mfma_f32_16x16x32_bf16(W1R[2 * ks],     ff, a1[0], 0, 0, 0);
                a1[1] = __builtin_amdgcn_mfma_f32_16x16x32_bf16(W1R[2 * ks + 1], ff, a1[1], 0, 0, 0);
            }

            // ---- tanh -> hidT (wave-private) ----
#pragma unroll
            for (int ot = 0; ot < 2; ++ot)
#pragma unroll
                for (int q = 0; q < 4; ++q) {
                    float e = __expf(2.f * a1[ot][q]);
                    hidT[wv][lm][ot * 16 + g * 4 + q] = 1.f - 2.f / (e + 1.f);
                }
            f32x4 h0v = *(const f32x4*)&hidT[wv][lm][g * 8];
            f32x4 h1v = *(const f32x4*)&hidT[wv][lm][g * 8 + 4];

            float pcv[9];
#pragma unroll
            for (int r = 0; r < 9; ++r) pcv[r] = S[r / 3 + hr][w0t + lm + (r % 3)];

            // ---- phase 2: out[o,pixel] = W2p @ (pc ⊗ hid) ----
            f32x4 a2[2] = {{0.f,0.f,0.f,0.f},{0.f,0.f,0.f,0.f}};
#pragma unroll
            for (int ks = 0; ks < 9; ++ks) {
                const float p = pcv[ks];
                i32x4 wd;
                wd[0] = (int)pk2(h0v[0] * p, h0v[1] * p);
                wd[1] = (int)pk2(h0v[2] * p, h0v[3] * p);
                wd[2] = (int)pk2(h1v[0] * p, h1v[1] * p);
                wd[3] = (int)pk2(h1v[2] * p, h1v[3] * p);
                bf16x8 ff2 = *(bf16x8*)&wd;
                a2[0] = __builtin_amdgcn_mfma_f32_16x16x32_bf16(W2R[2 * ks],     ff2, a2[0], 0, 0, 0);
                a2[1] = __builtin_amdgcn_mfma_f32_16x16x32_bf16(W2R[2 * ks + 1], ff2, a2[1], 0, 0, 0);
            }
            {   // ks==9: K-extension block (b2·pc + bias)
                i32x4 wd;
                wd[0] = (g == 0) ? (int)pk2(pcv[0], pcv[1]) : ((g == 1) ? (int)pk2(pcv[8], 1.f) : 0);
                wd[1] = (g == 0) ? (int)pk2(pcv[2], pcv[3]) : 0;
                wd[2] = (g == 0) ? (int)pk2(pcv[4], pcv[5]) : 0;
                wd[3] = (g == 0) ? (int)pk2(pcv[6], pcv[7]) : 0;
                bf16x8 ff2 = *(bf16x8*)&wd;
                a2[0] = __builtin_amdgcn_mfma_f32_16x16x32_bf16(W2R[18], ff2, a2[0], 0, 0, 0);
                a2[1] = __builtin_amdgcn_mfma_f32_16x16x32_bf16(W2R[19], ff2, a2[1], 0, 0, 0);
            }

            // ---- nontemporal stores straight from accumulator ----
            float* ob = out + b * (OO * LL) + (h0 + hr) * 256 + w0t + lm;
#pragma unroll
            for (int ot = 0; ot < 2; ++ot)
#pragma unroll
                for (int q = 0; q < 4; ++q)
                    __builtin_nontemporal_store(a2[ot][q], &ob[(ot * 16 + g * 4 + q) * LL]);
        }
    }
}

extern "C" void kernel_launch(void* const* d_in, const int* in_sizes, int n_in,
                              void* d_out, int out_size, void* d_ws, size_t ws_size,
                              hipStream_t stream) {
    const float* x    = (const float*)d_in[0];
    const float* W1   = (const float*)d_in[1];
    const float* b1   = (const float*)d_in[2];
    const float* W2   = (const float*)d_in[3];
    const float* b2   = (const float*)d_in[4];
    const float* bias = (const float*)d_in[5];
    float* out = (float*)d_out;

    ushort* w1f = (ushort*)d_ws;        // 5120 bf16
    ushort* w2f = w1f + 5120;           // 10240 bf16

    prepass<<<60, 256, 0, stream>>>(W1, b1, W2, b2, bias, w1f, w2f);
    dynaconv_mfma<<<512, 256, 0, stream>>>(x, w1f, w2f, out);
}